// Round 1
// baseline (70.971 us; speedup 1.0000x reference)
//
#include <hip/hip_runtime.h>
#include <math.h>

#define BATCH 8
#define G 256
#define A_TOT 32256
#define NBLK 126   // A_TOT / 256

// LO/HI bands per level: computed in double, truncated to f32 (matches np.float32(a*RATE))
__constant__ float c_LO[6] = {
    0.0f,
    (float)(0.32537674 * (22050.0 / 256.0)),
    (float)(0.47555801 * (22050.0 / 256.0)),
    (float)(0.64588683 * (22050.0 / 256.0)),
    (float)(1.16883525 * (22050.0 / 256.0)),
    (float)(2.17128976 * (22050.0 / 256.0)),
};
__constant__ float c_HI[6] = {
    (float)(0.32537674 * (22050.0 / 256.0)),
    (float)(0.47555801 * (22050.0 / 256.0)),
    (float)(0.64588683 * (22050.0 / 256.0)),
    (float)(1.16883525 * (22050.0 / 256.0)),
    (float)(2.17128976 * (22050.0 / 256.0)),
    INFINITY,
};

// Kernel 1: stable length-sort of annotations per sample via O(G^2) rank count.
__global__ void sort_ann_kernel(const float* __restrict__ ann, float2* __restrict__ sorted) {
    const int b = blockIdx.x;
    const int t = threadIdx.x;
    __shared__ float s_len[G];
    const float a0 = ann[(b * G + t) * 3 + 0];
    const float a1 = ann[(b * G + t) * 3 + 1];
    const float myLen = a1 - a0;
    s_len[t] = myLen;
    __syncthreads();
    int rank = 0;
#pragma unroll 8
    for (int k = 0; k < G; ++k) {
        const float lk = s_len[k];
        rank += (lk < myLen) || (lk == myLen && k < t);
    }
    sorted[b * G + rank] = make_float2(a0, a1);
}

// Kernel 2: one thread per anchor; first-match scan over sorted annotations; GIoU if positive.
__global__ void fcos_main_kernel(const float* __restrict__ reg,
                                 const float2* __restrict__ sorted,
                                 float* __restrict__ pLoss,
                                 float* __restrict__ pCnt) {
    const int bid = blockIdx.x;
    const int b = bid / NBLK;
    const int blk = bid % NBLK;
    const int t = threadIdx.x;

    __shared__ float2 s_ann[G];
    s_ann[t] = sorted[b * G + t];
    __syncthreads();

    const int aidx = blk * 256 + t;
    int lvl, off;
    if (aidx < 16384)      { lvl = 0; off = 0; }
    else if (aidx < 24576) { lvl = 1; off = 16384; }
    else if (aidx < 28672) { lvl = 2; off = 24576; }
    else if (aidx < 30720) { lvl = 3; off = 28672; }
    else if (aidx < 31744) { lvl = 4; off = 30720; }
    else                   { lvl = 5; off = 31744; }

    const float p  = (float)(aidx - off) * (float)(1 << lvl);  // exact: arange(n)*2^i
    const float lo = c_LO[lvl];
    const float hi = c_HI[lvl];

    float a0 = 0.f, a1 = 0.f;
    bool found = false;
    for (int j = 0; j < G; ++j) {
        const float2 aj = s_ann[j];
        const float l = p - aj.x;
        const float r = aj.y - p;
        const float m = fmaxf(l, r);
        if (l >= 0.f && r >= 0.f && m >= lo && m < hi) {
            a0 = aj.x; a1 = aj.y; found = true; break;
        }
    }

    float loss = 0.f, cnt = 0.f;
    if (found) {
        const float scale = 1.0f / (float)(1 << lvl);  // exact pow2 reciprocal
        a0 *= scale; a1 *= scale;
        const float b0 = reg[(b * A_TOT + aidx) * 2 + 0];
        const float b1 = reg[(b * A_TOT + aidx) * 2 + 1];
        const float inter = fmaxf(fminf(a1, b1) - fmaxf(a0, b0), 0.f);
        const float uni   = (a1 - a0) + (b1 - b0) - inter;
        const float enc   = fmaxf(a1, b1) - fminf(a0, b0);
        const float iou   = inter / (uni + 1e-7f);
        const float giou  = iou - (enc - uni) / (enc + 1e-7f);
        loss = 1.0f - giou;
        cnt  = 1.0f;
    }

    __shared__ float r_loss[256];
    __shared__ float r_cnt[256];
    r_loss[t] = loss;
    r_cnt[t]  = cnt;
    __syncthreads();
    for (int s = 128; s > 0; s >>= 1) {
        if (t < s) { r_loss[t] += r_loss[t + s]; r_cnt[t] += r_cnt[t + s]; }
        __syncthreads();
    }
    if (t == 0) { pLoss[bid] = r_loss[0]; pCnt[bid] = r_cnt[0]; }
}

// Kernel 3: deterministic final reduction of 126 partials per sample.
__global__ void finalize_kernel(const float* __restrict__ pLoss,
                                const float* __restrict__ pCnt,
                                float* __restrict__ out) {
    const int b = blockIdx.x;
    const int t = threadIdx.x;  // 128 threads
    float s = 0.f, c = 0.f;
    for (int i = t; i < NBLK; i += 128) {
        s += pLoss[b * NBLK + i];
        c += pCnt[b * NBLK + i];
    }
    __shared__ float r_s[128];
    __shared__ float r_c[128];
    r_s[t] = s; r_c[t] = c;
    __syncthreads();
    for (int st = 64; st > 0; st >>= 1) {
        if (t < st) { r_s[t] += r_s[t + st]; r_c[t] += r_c[t + st]; }
        __syncthreads();
    }
    if (t == 0) out[b] = r_s[0] / fmaxf(r_c[0], 1.0f);
}

extern "C" void kernel_launch(void* const* d_in, const int* in_sizes, int n_in,
                              void* d_out, int out_size, void* d_ws, size_t ws_size,
                              hipStream_t stream) {
    const float* reg = (const float*)d_in[0];   // (B, A, 2)
    const float* ann = (const float*)d_in[1];   // (B, G, 3)
    float* out = (float*)d_out;                 // (B,)

    float2* sorted = (float2*)d_ws;                                   // B*G float2 = 16 KB
    float*  pLoss  = (float*)((char*)d_ws + BATCH * G * sizeof(float2));
    float*  pCnt   = pLoss + BATCH * NBLK;

    sort_ann_kernel<<<BATCH, G, 0, stream>>>(ann, sorted);
    fcos_main_kernel<<<BATCH * NBLK, 256, 0, stream>>>(reg, sorted, pLoss, pCnt);
    finalize_kernel<<<BATCH, 128, 0, stream>>>(pLoss, pCnt, out);
}

// Round 2
// 28.734 us; speedup vs baseline: 2.4699x; 2.4699x over previous
//
#include <hip/hip_runtime.h>
#include <math.h>

#define BATCH 8
#define G 256
#define A_TOT 32256
#define NBLK 126   // A_TOT / 256

// LO/HI bands per level: computed in double, truncated to f32 (matches np.float32(a*RATE))
__constant__ float c_LO[6] = {
    0.0f,
    (float)(0.32537674 * (22050.0 / 256.0)),
    (float)(0.47555801 * (22050.0 / 256.0)),
    (float)(0.64588683 * (22050.0 / 256.0)),
    (float)(1.16883525 * (22050.0 / 256.0)),
    (float)(2.17128976 * (22050.0 / 256.0)),
};
__constant__ float c_HI[6] = {
    (float)(0.32537674 * (22050.0 / 256.0)),
    (float)(0.47555801 * (22050.0 / 256.0)),
    (float)(0.64588683 * (22050.0 / 256.0)),
    (float)(1.16883525 * (22050.0 / 256.0)),
    (float)(2.17128976 * (22050.0 / 256.0)),
    INFINITY,
};

// Kernel 1: stable length-sort per sample (O(G^2) rank count) + per-level
// candidate ranges [jlo, jhi) via binary search over sorted lengths.
// An annotation can only match level i if len in [LO_i, 2*HI_i) (m = max(l,r)
// lies in [len/2, len] for in-box anchors). 0.01 margin covers fp32 rounding.
__global__ void sort_ann_kernel(const float* __restrict__ ann,
                                float2* __restrict__ sorted,
                                int2* __restrict__ ranges) {
    const int b = blockIdx.x;
    const int t = threadIdx.x;
    __shared__ float  s_len[G];
    __shared__ float  s_slen[G];
    __shared__ float2 s_sorted[G];

    const float a0 = ann[(b * G + t) * 3 + 0];
    const float a1 = ann[(b * G + t) * 3 + 1];
    const float myLen = a1 - a0;
    s_len[t] = myLen;
    __syncthreads();
    int rank = 0;
#pragma unroll 8
    for (int k = 0; k < G; ++k) {
        const float lk = s_len[k];
        rank += (lk < myLen) || (lk == myLen && k < t);
    }
    s_sorted[rank] = make_float2(a0, a1);
    s_slen[rank] = myLen;
    __syncthreads();

    sorted[b * G + t] = s_sorted[t];

    if (t < 6) {
        const float xlo = c_LO[t] - 0.01f;
        const float xhi = 2.0f * c_HI[t] + 0.01f;  // inf stays inf
        // lower_bound: first idx with s_slen[idx] >= x
        int lo = 0, hi = G;
        while (lo < hi) { int mid = (lo + hi) >> 1; if (s_slen[mid] < xlo) lo = mid + 1; else hi = mid; }
        int jlo = lo;
        lo = jlo; hi = G;
        while (lo < hi) { int mid = (lo + hi) >> 1; if (s_slen[mid] < xhi) lo = mid + 1; else hi = mid; }
        ranges[b * 6 + t] = make_int2(jlo, lo);
    }
}

// Kernel 2: one thread per anchor; branchless min-index first-match scan over
// the level's candidate range; GIoU only for positives; block reduction.
__global__ void fcos_main_kernel(const float* __restrict__ reg,
                                 const float2* __restrict__ sorted,
                                 const int2* __restrict__ ranges,
                                 float* __restrict__ pLoss,
                                 float* __restrict__ pCnt) {
    const int bid = blockIdx.x;
    const int b = bid / NBLK;
    const int blk = bid % NBLK;
    const int t = threadIdx.x;

    __shared__ float2 s_ann[G];
    s_ann[t] = sorted[b * G + t];

    // level is uniform per block (boundaries are multiples of 256)
    const int aidx0 = blk * 256;
    int lvl, off;
    if (aidx0 < 16384)      { lvl = 0; off = 0; }
    else if (aidx0 < 24576) { lvl = 1; off = 16384; }
    else if (aidx0 < 28672) { lvl = 2; off = 24576; }
    else if (aidx0 < 30720) { lvl = 3; off = 28672; }
    else if (aidx0 < 31744) { lvl = 4; off = 30720; }
    else                    { lvl = 5; off = 31744; }

    const int aidx = aidx0 + t;
    const float p  = (float)(aidx - off) * (float)(1 << lvl);  // exact
    const float lo = c_LO[lvl];
    const float hi = c_HI[lvl];
    const int2 rg = ranges[b * 6 + lvl];
    __syncthreads();

    int bestJ = 0x7FFFFFFF;
#pragma unroll 4
    for (int j = rg.x; j < rg.y; ++j) {
        const float2 aj = s_ann[j];
        const float l = p - aj.x;
        const float r = aj.y - p;
        const float mn = fminf(l, r);
        const float m  = fmaxf(l, r);
        const bool c = (mn >= 0.f) & (m >= lo) & (m < hi);
        if (c) bestJ = min(bestJ, j);
    }

    float loss = 0.f, cnt = 0.f;
    if (bestJ != 0x7FFFFFFF) {
        const float2 aj = s_ann[bestJ];
        const float scale = 1.0f / (float)(1 << lvl);  // exact pow2
        const float a0 = aj.x * scale;
        const float a1 = aj.y * scale;
        const float b0 = reg[(b * A_TOT + aidx) * 2 + 0];
        const float b1 = reg[(b * A_TOT + aidx) * 2 + 1];
        const float inter = fmaxf(fminf(a1, b1) - fmaxf(a0, b0), 0.f);
        const float uni   = (a1 - a0) + (b1 - b0) - inter;
        const float enc   = fmaxf(a1, b1) - fminf(a0, b0);
        const float iou   = inter / (uni + 1e-7f);
        const float giou  = iou - (enc - uni) / (enc + 1e-7f);
        loss = 1.0f - giou;
        cnt  = 1.0f;
    }

    __shared__ float r_loss[256];
    __shared__ float r_cnt[256];
    r_loss[t] = loss;
    r_cnt[t]  = cnt;
    __syncthreads();
    for (int s = 128; s > 0; s >>= 1) {
        if (t < s) { r_loss[t] += r_loss[t + s]; r_cnt[t] += r_cnt[t + s]; }
        __syncthreads();
    }
    if (t == 0) { pLoss[bid] = r_loss[0]; pCnt[bid] = r_cnt[0]; }
}

// Kernel 3: deterministic final reduction of 126 partials per sample.
__global__ void finalize_kernel(const float* __restrict__ pLoss,
                                const float* __restrict__ pCnt,
                                float* __restrict__ out) {
    const int b = blockIdx.x;
    const int t = threadIdx.x;  // 128 threads
    float s = 0.f, c = 0.f;
    for (int i = t; i < NBLK; i += 128) {
        s += pLoss[b * NBLK + i];
        c += pCnt[b * NBLK + i];
    }
    __shared__ float r_s[128];
    __shared__ float r_c[128];
    r_s[t] = s; r_c[t] = c;
    __syncthreads();
    for (int st = 64; st > 0; st >>= 1) {
        if (t < st) { r_s[t] += r_s[t + st]; r_c[t] += r_c[t + st]; }
        __syncthreads();
    }
    if (t == 0) out[b] = r_s[0] / fmaxf(r_c[0], 1.0f);
}

extern "C" void kernel_launch(void* const* d_in, const int* in_sizes, int n_in,
                              void* d_out, int out_size, void* d_ws, size_t ws_size,
                              hipStream_t stream) {
    const float* reg = (const float*)d_in[0];   // (B, A, 2)
    const float* ann = (const float*)d_in[1];   // (B, G, 3)
    float* out = (float*)d_out;                 // (B,)

    float2* sorted = (float2*)d_ws;                                    // B*G float2 = 16 KB
    int2*   ranges = (int2*)((char*)d_ws + BATCH * G * sizeof(float2));// B*6 int2
    float*  pLoss  = (float*)((char*)ranges + BATCH * 6 * sizeof(int2));
    float*  pCnt   = pLoss + BATCH * NBLK;

    sort_ann_kernel<<<BATCH, G, 0, stream>>>(ann, sorted, ranges);
    fcos_main_kernel<<<BATCH * NBLK, 256, 0, stream>>>(reg, sorted, ranges, pLoss, pCnt);
    finalize_kernel<<<BATCH, 128, 0, stream>>>(pLoss, pCnt, out);
}